// Round 9
// baseline (693.863 us; speedup 1.0000x reference)
//
#include <hip/hip_runtime.h>

// DAG-GRU encoder, dispatch-independent persistent kernel + separate mu/logvar
// GEMV kernel. B=16, S=64, H=1024, C=16.
// enc_kernel: 8 groups (= blockIdx>>5) x 32 blocks; group g owns batches
// {2g,2g+1}. Each block: 32-o output tile, all 5 weight rows in VGPRs as fp16
// pairs (160 VGPRs). amdgpu_waves_per_eu(2,2) pins occupancy to 1 block/CU so
// the allocator gets the 256-VGPR budget (r7/r8 spilled: LDS allowed 2
// blocks/CU -> compiler targeted 4 waves/EU -> 128-VGPR cap -> 72MB scratch).
// Per step: phase A (G/M row GEMV + LDS masked scan -> h_in), phase B
// (gh GEMV + GRU pointwise -> hv). Cross-block exchange via sc0/sc1
// (Infinity-Cache) ops; single-writer flags, no fences (r5/r6 evidence).
// kF: separate kernel computing mu/logvar from the validated f32 hv in out.

#define NT 512
#define NBLK 256

typedef unsigned int uint;
typedef __attribute__((ext_vector_type(2))) _Float16 half2v;
typedef __attribute__((ext_vector_type(4))) uint uint4v;

__device__ __forceinline__ float fdot2(uint w, uint h, float acc) {
#if __has_builtin(__builtin_amdgcn_fdot2)
    return __builtin_amdgcn_fdot2(__builtin_bit_cast(half2v, w),
                                  __builtin_bit_cast(half2v, h), acc, false);
#else
    half2v a = __builtin_bit_cast(half2v, w);
    half2v b = __builtin_bit_cast(half2v, h);
    return acc + (float)a[0] * (float)b[0] + (float)a[1] * (float)b[1];
#endif
}

__device__ __forceinline__ uint packh2(float a, float b) {
    half2v h; h[0] = (_Float16)a; h[1] = (_Float16)b;
    return __builtin_bit_cast(uint, h);
}

__device__ __forceinline__ float sigm(float x) { return 1.0f / (1.0f + __expf(-x)); }
__device__ __forceinline__ float tanhfast(float x) { return 2.0f / (1.0f + __expf(-2.0f * x)) - 1.0f; }

// issue 8x dwordx4 device-coherent loads (bypass L1+L2 -> IF), NO wait
#define LD8_ISSUE(hx, baseptr)                                                 \
    asm volatile("global_load_dwordx4 %0, %8, off sc0 sc1\n\t"                 \
                 "global_load_dwordx4 %1, %8, off offset:16 sc0 sc1\n\t"       \
                 "global_load_dwordx4 %2, %8, off offset:32 sc0 sc1\n\t"       \
                 "global_load_dwordx4 %3, %8, off offset:48 sc0 sc1\n\t"       \
                 "global_load_dwordx4 %4, %8, off offset:64 sc0 sc1\n\t"       \
                 "global_load_dwordx4 %5, %8, off offset:80 sc0 sc1\n\t"       \
                 "global_load_dwordx4 %6, %8, off offset:96 sc0 sc1\n\t"       \
                 "global_load_dwordx4 %7, %8, off offset:112 sc0 sc1"          \
                 : "=&v"(hx[0]), "=&v"(hx[1]), "=&v"(hx[2]), "=&v"(hx[3]),     \
                   "=&v"(hx[4]), "=&v"(hx[5]), "=&v"(hx[6]), "=&v"(hx[7])      \
                 : "v"(baseptr) : "memory")

#define WAIT_VM8()                                          \
    asm volatile("s_waitcnt vmcnt(8)" ::: "memory");        \
    __builtin_amdgcn_sched_barrier(0)
#define WAIT_VM0()                                          \
    asm volatile("s_waitcnt vmcnt(0)" ::: "memory");        \
    __builtin_amdgcn_sched_barrier(0)

__device__ __forceinline__ void st_dev_wait(uint* p, uint v) {
    asm volatile("global_store_dword %0, %1, off sc0 sc1\n\ts_waitcnt vmcnt(0)"
                 :: "v"(p), "v"(v) : "memory");
}

__device__ __forceinline__ void st_flag(int* p, int v) {
    asm volatile("global_store_dword %0, %1, off sc0 sc1\n\ts_waitcnt vmcnt(0)"
                 :: "v"(p), "v"(v) : "memory");
}

// All threads call. Wave 0 (lanes 0..31) polls the group's 32 single-writer
// flag words until all >= gen; __syncthreads extends to the whole block.
__device__ __forceinline__ void wait_flags(const int* fl, int gen) {
    if (threadIdx.x < 64) {
        const int lane = threadIdx.x;
        bool done;
        do {
            int v = gen;
            if (lane < 32) {
                const int* pp = fl + lane;
                asm volatile("global_load_dword %0, %1, off sc0 sc1\n\ts_waitcnt vmcnt(0)"
                             : "=v"(v) : "v"(pp) : "memory");
            }
            done = __all(v >= gen);
        } while (!done);
    }
    __syncthreads();
}

__device__ __forceinline__ void loadw(uint* arr, const float* rowk) {
    const float4* s4 = (const float4*)rowk;
#pragma unroll
    for (int j = 0; j < 16; j++) {
        float4 v = s4[j];
        arr[2 * j]     = packh2(v.x, v.y);
        arr[2 * j + 1] = packh2(v.z, v.w);
    }
}

__global__ __launch_bounds__(NT)
__attribute__((amdgpu_waves_per_eu(2, 2)))
void enc_kernel(
    const float* __restrict__ dep, const float* __restrict__ ne,
    const float* __restrict__ gate_w, const float* __restrict__ gate_b,
    const float* __restrict__ map_w, const float* __restrict__ map_b,
    const float* __restrict__ w_ih, const float* __restrict__ w_hh,
    const float* __restrict__ b_ih, const float* __restrict__ b_hh,
    int* __restrict__ flags, uint* __restrict__ hv_ex, uint* __restrict__ hin_ex,
    float* __restrict__ out)
{
    __shared__ __align__(16) float smem[13888];
    float* GM   = smem;                   // [4][64][33]: (mat*2+b, s, ol) f32
    float* red  = smem + 8448;            // 1536: cross-wave partials
    float* hbuf = smem + 9984;            // [2][32]: h_in / hv staging
    float* wihb = smem + 10048;           // [3][32][16] w_ih slice
    float* neb  = smem + 11584;           // [2][64][16] node_encoding slice
    uint*  depb = (uint*)(smem + 13632);  // [2][64][2] mask bits

    const int tid = threadIdx.x;
    const int bid = blockIdx.x;
    const int gid = bid >> 5;          // group = batch pair (dispatch-independent)
    const int p   = bid & 31;          // o-tile slot in group
    const int o0  = p * 32;
    const int bg0 = gid * 2;

    int*  fl   = flags  + gid * 32;
    uint* hvx  = hv_ex  + gid * 1024;  // [2][512] uints (fp16 pairs)
    uint* hinx = hin_ex + gid * 1024;

    const int w     = tid >> 6;        // wave = k-chunk of 128
    const int lane  = tid & 63;
    const int ol2   = lane >> 1;       // GEMV lane's o within tile
    const int kh    = lane & 1;
    const int og    = o0 + ol2;
    const int kbase = w * 128 + kh * 64;

    // ---- weights -> registers (fp16 packed), 160 VGPRs ----
    uint wG[32], wM[32], wR[32], wZ[32], wN[32];
    loadw(wG, gate_w + og * 1024 + kbase);
    loadw(wM, map_w + og * 1024 + kbase);
    loadw(wR, w_hh + og * 1024 + kbase);
    loadw(wZ, w_hh + (1024 + og) * 1024 + kbase);
    loadw(wN, w_hh + (2048 + og) * 1024 + kbase);

    // ---- LDS tables ----
    if (tid < 256) {  // dep bitmask: [b][t][half32]
        int b = tid >> 7, tt = (tid >> 1) & 63, hf = tid & 1;
        const float* dp = dep + (((bg0 + b) * 64 + tt) * 64) + hf * 32;
        uint bits = 0;
        for (int s = 0; s < 32; s++) bits |= (dp[s] != 0.0f) ? (1u << s) : 0u;
        depb[tid] = bits;
    }
#pragma unroll
    for (int e = 0; e < 3; e++) {     // w_ih slice [g][ol][c]
        int idx = tid + e * 512;
        int g = idx >> 9, r = idx & 511;
        wihb[idx] = w_ih[(g * 1024 + o0 + (r >> 4)) * 16 + (r & 15)];
    }
#pragma unroll
    for (int e = 0; e < 4; e++) {     // ne slice [b][t][c]
        int idx = tid + e * 512;
        int b = idx >> 10, r = idx & 1023;
        neb[idx] = ne[(bg0 + b) * 1024 + r];
    }

    // ---- hoisted per-thread scalars ----
    const int ol_s = (tid >> 3) & 31;
    const int b_s  = tid >> 8;
    const int soct = tid & 7;
    const float gb_s   = gate_b[o0 + ol_s];
    const float mb_s   = map_b[o0 + ol_s];
    const float base_s = sigm(gb_s) * mb_s;
    const int ol_c = tid & 31, b_c = (tid >> 5) & 1;
    const int oc = o0 + ol_c;
    const float bir = b_ih[oc], biz = b_ih[1024 + oc], bin_ = b_ih[2048 + oc];
    const float bhr = b_hh[oc], bhz = b_hh[1024 + oc], bhn = b_hh[2048 + oc];
    __syncthreads();

    for (int t = 0; t < 64; t++) {
        // ===== phase A: G/M row t-1 GEMV (regs) + masked scan -> h_in =====
        if (t > 0) {
            wait_flags(fl, 2 * t);     // hv of step t-1 published everywhere
            float aG0 = 0, aG1 = 0, aM0 = 0, aM1 = 0;
            {
                uint4v hxA[8], hxB[8];
                LD8_ISSUE(hxA, hvx + w * 64 + kh * 32);        // b0 hv slice
                LD8_ISSUE(hxB, hvx + 512 + w * 64 + kh * 32);  // b1 hv slice
                WAIT_VM8();
#pragma unroll
                for (int j = 0; j < 8; j++)
#pragma unroll
                    for (int q = 0; q < 4; q++) {
                        uint h = hxA[j][q];
                        aG0 = fdot2(wG[j * 4 + q], h, aG0);
                        aM0 = fdot2(wM[j * 4 + q], h, aM0);
                    }
                WAIT_VM0();
#pragma unroll
                for (int j = 0; j < 8; j++)
#pragma unroll
                    for (int q = 0; q < 4; q++) {
                        uint h = hxB[j][q];
                        aG1 = fdot2(wG[j * 4 + q], h, aG1);
                        aM1 = fdot2(wM[j * 4 + q], h, aM1);
                    }
            }
            aG0 += __shfl_xor(aG0, 1, 64); aG1 += __shfl_xor(aG1, 1, 64);
            aM0 += __shfl_xor(aM0, 1, 64); aM1 += __shfl_xor(aM1, 1, 64);
            if (kh == 0) {
                red[(w * 4 + 0) * 32 + ol2] = aG0;
                red[(w * 4 + 1) * 32 + ol2] = aG1;
                red[(w * 4 + 2) * 32 + ol2] = aM0;
                red[(w * 4 + 3) * 32 + ol2] = aM1;
            }
            __syncthreads();
            if (tid < 128) {   // mb2 = tid>>5: {G b0, G b1, M b0, M b1}
                int mb2 = tid >> 5, olr = tid & 31;
                float s = 0;
#pragma unroll
                for (int ww = 0; ww < 8; ww++) s += red[(ww * 4 + mb2) * 32 + olr];
                GM[(mb2 * 64 + (t - 1)) * 33 + olr] = s;
            }
            __syncthreads();
        }

        {   // masked scan: 8 threads per (b,o), 8 s each; GM in LDS
            uint bl = depb[b_s * 128 + t * 2 + (soct >> 2)];
            uint bits8 = (bl >> ((soct & 3) * 8)) & 0xFFu;
            const float* Gp = GM + (b_s * 64 + soct * 8) * 33 + ol_s;
            const float* Mp = GM + ((2 + b_s) * 64 + soct * 8) * 33 + ol_s;
            float part = 0.0f;
#pragma unroll
            for (int j = 0; j < 8; j++) {
                float Gv = Gp[j * 33], Mv = Mp[j * 33];
                float term = ((bits8 >> j) & 1u) ? (sigm(Gv + gb_s) * (Mv + mb_s)) : base_s;
                part += term;
            }
            part += __shfl_xor(part, 1, 64);
            part += __shfl_xor(part, 2, 64);
            part += __shfl_xor(part, 4, 64);
            if ((tid & 7) == 0) hbuf[b_s * 32 + ol_s] = part;
        }
        __syncthreads();
        if (tid < 32) {   // publish h_in slice (fp16 pairs)
            int bb = tid >> 4, j = tid & 15;
            uint pk = packh2(hbuf[bb * 32 + 2 * j], hbuf[bb * 32 + 2 * j + 1]);
            st_dev_wait(hinx + bb * 512 + p * 16 + j, pk);
        }
        __syncthreads();
        if (tid == 0) st_flag(fl + p, 2 * t + 1);

        // ===== phase B: gh GEMV (regs) + GRU pointwise -> hv =====
        wait_flags(fl, 2 * t + 1);
        float ar0 = 0, ar1 = 0, az0 = 0, az1 = 0, an0 = 0, an1 = 0;
        {
            uint4v hxA[8], hxB[8];
            LD8_ISSUE(hxA, hinx + w * 64 + kh * 32);
            LD8_ISSUE(hxB, hinx + 512 + w * 64 + kh * 32);
            WAIT_VM8();
#pragma unroll
            for (int j = 0; j < 8; j++)
#pragma unroll
                for (int q = 0; q < 4; q++) {
                    uint h = hxA[j][q];
                    ar0 = fdot2(wR[j * 4 + q], h, ar0);
                    az0 = fdot2(wZ[j * 4 + q], h, az0);
                    an0 = fdot2(wN[j * 4 + q], h, an0);
                }
            WAIT_VM0();
#pragma unroll
            for (int j = 0; j < 8; j++)
#pragma unroll
                for (int q = 0; q < 4; q++) {
                    uint h = hxB[j][q];
                    ar1 = fdot2(wR[j * 4 + q], h, ar1);
                    az1 = fdot2(wZ[j * 4 + q], h, az1);
                    an1 = fdot2(wN[j * 4 + q], h, an1);
                }
        }
        ar0 += __shfl_xor(ar0, 1, 64); ar1 += __shfl_xor(ar1, 1, 64);
        az0 += __shfl_xor(az0, 1, 64); az1 += __shfl_xor(az1, 1, 64);
        an0 += __shfl_xor(an0, 1, 64); an1 += __shfl_xor(an1, 1, 64);
        if (kh == 0) {
            red[(w * 6 + 0) * 32 + ol2] = ar0;
            red[(w * 6 + 1) * 32 + ol2] = ar1;
            red[(w * 6 + 2) * 32 + ol2] = az0;
            red[(w * 6 + 3) * 32 + ol2] = az1;
            red[(w * 6 + 4) * 32 + ol2] = an0;
            red[(w * 6 + 5) * 32 + ol2] = an1;
        }
        __syncthreads();
        if (tid < 64) {
            float ghr = 0, ghz = 0, ghn = 0;
#pragma unroll
            for (int ww = 0; ww < 8; ww++) {
                ghr += red[(ww * 6 + 0 + b_c) * 32 + ol_c];
                ghz += red[(ww * 6 + 2 + b_c) * 32 + ol_c];
                ghn += red[(ww * 6 + 4 + b_c) * 32 + ol_c];
            }
            float gi0 = 0, gi1 = 0, gi2 = 0;
#pragma unroll
            for (int c = 0; c < 16; c++) {
                float xv = neb[b_c * 1024 + t * 16 + c];
                gi0 += wihb[ol_c * 16 + c] * xv;
                gi1 += wihb[512 + ol_c * 16 + c] * xv;
                gi2 += wihb[1024 + ol_c * 16 + c] * xv;
            }
            float h_in = hbuf[b_c * 32 + ol_c];
            float r = sigm(gi0 + bir + ghr + bhr);
            float z = sigm(gi1 + biz + ghz + bhz);
            float n = tanhfast(gi2 + bin_ + r * (ghn + bhn));
            float hv = (1.0f - z) * n + z * h_in;
            if (t == 63) out[(bg0 + b_c) * 1024 + oc] = hv;
            hbuf[b_c * 32 + ol_c] = hv;
        }
        __syncthreads();
        if (t < 63) {
            if (tid < 32) {   // publish hv slice
                int bb = tid >> 4, j = tid & 15;
                uint pk = packh2(hbuf[bb * 32 + 2 * j], hbuf[bb * 32 + 2 * j + 1]);
                st_dev_wait(hvx + bb * 512 + p * 16 + j, pk);
            }
            __syncthreads();
            if (tid == 0) st_flag(fl + p, 2 * t + 2);
        }
    }
    // mu/logvar computed by kF (separate dispatch) from the f32 hv in out.
}

__device__ __forceinline__ float wave_sum(float v) {
    v += __shfl_xor(v, 32, 64);
    v += __shfl_xor(v, 16, 64);
    v += __shfl_xor(v, 8, 64);
    v += __shfl_xor(v, 4, 64);
    v += __shfl_xor(v, 2, 64);
    v += __shfl_xor(v, 1, 64);
    return v;
}

// mu/logvar: out[16K..32K) = hv @ l1w^T + b1, out[32K..48K) = hv @ l2w^T + b2.
__global__ __launch_bounds__(256) void kF(
    float* out, const float* __restrict__ w1, const float* __restrict__ b1,
    const float* __restrict__ w2, const float* __restrict__ b2)
{
    const int wid = threadIdx.x >> 6;
    const int kl = threadIdx.x & 63;
    const int o = blockIdx.x * 2 + (wid >> 1);
    const int b0 = (wid & 1) * 8;

    float w1v[16], w2v[16];
#pragma unroll
    for (int i = 0; i < 16; i++) {
        w1v[i] = w1[o * 1024 + kl + 64 * i];
        w2v[i] = w2[o * 1024 + kl + 64 * i];
    }
    for (int b = b0; b < b0 + 8; b++) {
        float p1 = 0.0f, p2 = 0.0f;
#pragma unroll
        for (int i = 0; i < 16; i++) {
            float h = out[b * 1024 + kl + 64 * i];
            p1 += h * w1v[i];
            p2 += h * w2v[i];
        }
        p1 = wave_sum(p1);
        p2 = wave_sum(p2);
        if (kl == 0) {
            out[16384 + b * 1024 + o] = p1 + b1[o];
            out[32768 + b * 1024 + o] = p2 + b2[o];
        }
    }
}

extern "C" void kernel_launch(void* const* d_in, const int* in_sizes, int n_in,
                              void* d_out, int out_size, void* d_ws, size_t ws_size,
                              hipStream_t stream) {
    const float* dep     = (const float*)d_in[0];
    const float* ne      = (const float*)d_in[1];
    const float* gate_w  = (const float*)d_in[2];
    const float* gate_b  = (const float*)d_in[3];
    const float* map_w   = (const float*)d_in[4];
    const float* map_b   = (const float*)d_in[5];
    const float* w_ih    = (const float*)d_in[6];
    const float* w_hh    = (const float*)d_in[7];
    const float* b_ih    = (const float*)d_in[8];
    const float* b_hh    = (const float*)d_in[9];
    const float* lin11_w = (const float*)d_in[10];
    const float* lin11_b = (const float*)d_in[11];
    const float* lin12_w = (const float*)d_in[12];
    const float* lin12_b = (const float*)d_in[13];

    int* wsI = (int*)d_ws;
    int* flags   = wsI;                      // [8][32] ints
    uint* hv_ex  = (uint*)(wsI + 256);       // [8][2][512]
    uint* hin_ex = hv_ex + 8192;             // [8][2][512]
    float* outp  = (float*)d_out;

    hipMemsetAsync((void*)flags, 0, 256 * 4, stream);

    void* args[] = {
        (void*)&dep, (void*)&ne, (void*)&gate_w, (void*)&gate_b,
        (void*)&map_w, (void*)&map_b, (void*)&w_ih, (void*)&w_hh,
        (void*)&b_ih, (void*)&b_hh,
        (void*)&flags, (void*)&hv_ex, (void*)&hin_ex, (void*)&outp,
    };
    hipError_t e = hipLaunchCooperativeKernel((void*)enc_kernel, dim3(NBLK), dim3(NT),
                                              args, 0, stream);
    if (e != hipSuccess) {
        enc_kernel<<<dim3(NBLK), dim3(NT), 0, stream>>>(
            dep, ne, gate_w, gate_b, map_w, map_b, w_ih, w_hh, b_ih, b_hh,
            flags, hv_ex, hin_ex, outp);
    }
    kF<<<dim3(512), dim3(256), 0, stream>>>(outp, lin11_w, lin11_b, lin12_w, lin12_b);
}